// Round 6
// baseline (334.807 us; speedup 1.0000x reference)
//
#include <hip/hip_runtime.h>
#include <hip/hip_bf16.h>
#include <cstdint>
#include <cstddef>

#define NQ 8192
#define NK 8192
#define DD 64
#define KSPLIT 4
#define KRANGE (NK / KSPLIT)   // 2048
#define KTILE 128
#define NT (KRANGE / KTILE)    // 16

typedef __bf16 bf16x8 __attribute__((ext_vector_type(8)));
typedef float f32x16 __attribute__((ext_vector_type(16)));
typedef unsigned short u16;
typedef uint32_t u32;

static __device__ __forceinline__ u16 f2bf(float f) {
    union { float f; uint32_t u; } v; v.f = f;
    uint32_t r = (v.u + 0x7fffu + ((v.u >> 16) & 1u)) >> 16;
    return (u16)r;
}

static __device__ __forceinline__ u32 cvtpk(float lo, float hi) {
    u32 r;
    asm("v_cvt_pk_bf16_f32 %0, %1, %2" : "=v"(r) : "v"(lo), "v"(hi));
    return r;
}

#define GLOAD16(g, l)                                                          \
    __builtin_amdgcn_global_load_lds(                                          \
        (__attribute__((address_space(1))) void*)(g),                          \
        (__attribute__((address_space(3))) void*)(l), 16, 0, 0)

// ---------------- Kernel 1: L2-normalize Q and K rows -> bf16 ----------------
__global__ void k_norm(const float* __restrict__ q, const float* __restrict__ k,
                       u16* __restrict__ qn, u16* __restrict__ kn) {
    int wid  = (blockIdx.x * blockDim.x + threadIdx.x) >> 6;
    int lane = threadIdx.x & 63;                 // lane == d (D == 64)
    int nw   = (gridDim.x * blockDim.x) >> 6;
    for (int row = wid; row < 2 * NQ; row += nw) {
        const float* src = (row < NQ) ? q : k;
        u16* dst = (row < NQ) ? qn : kn;
        int r = row & (NQ - 1);
        float x = src[(size_t)r * DD + lane];
        float ss = x * x;
        #pragma unroll
        for (int m = 1; m < 64; m <<= 1) ss += __shfl_xor(ss, m, 64);
        dst[(size_t)r * DD + lane] = f2bf(x * rsqrtf(ss));
    }
}

// ---------------- Kernel 2: transpose V -> vT[d][m] bf16 ----------------
__global__ void k_transv(const float* __restrict__ v, u16* __restrict__ vT) {
    __shared__ float ts[64][65];
    int mb = blockIdx.x * 64;
    int t = threadIdx.x;
    #pragma unroll
    for (int i = 0; i < 16; i++) {
        int idx = i * 256 + t;
        int r = idx >> 6, c = idx & 63;
        ts[r][c] = v[(size_t)(mb + r) * DD + c];
    }
    __syncthreads();
    #pragma unroll
    for (int i = 0; i < 16; i++) {
        int idx = i * 256 + t;
        int d = idx >> 6, m = idx & 63;
        vT[(size_t)d * NK + mb + m] = f2bf(ts[m][d]);
    }
}

// ---------------- Kernel 3: flash pass (split-K, 2-phase dbuf) ---------------
// Grid 1024: block = (qi, sp); 32 q-rows, keys [sp*2048, (sp+1)*2048).
// 2-phase pipeline: STAGE(next buf) issued BEFORE compute(cur); the single
// __syncthreads per iter drains vmcnt — loads overlap MFMA+exp (T3 minimum).
__global__ __launch_bounds__(256, 2) void
k_flash(const u16* __restrict__ qn, const u16* __restrict__ kn,
        const u16* __restrict__ vT, const int* __restrict__ hcp,
        float* __restrict__ prs, float* __restrict__ ppv) {
    __shared__ __align__(16) u16 qs[32 * 64];          // 4 KB
    __shared__ __align__(16) union SmT {
        struct { u16 ks[128 * 64]; u16 vs[64 * 128]; } t[2];    // 64 KB dbuf
        struct { float redA[32 * 64]; float redB[32 * 64]; } ep; // 16 KB epi
    } sm;
    __shared__ float rs_ws[4][32];

    const float hc = (float)hcp[0];
    const int t = threadIdx.x;
    const int w = t >> 6;
    const int lane = t & 63;
    const int l31 = lane & 31;
    const int half = lane >> 5;
    const int qb = (blockIdx.x >> 2) * 32;
    const int sp = blockIdx.x & 3;
    const int k0 = sp * KRANGE;
    const int kw = w * 32;     // this wave's k-chunk within the 128 tile

#define STAGE_KV(B, KB)                                                        \
    do {                                                                       \
        const u16* ksrc_ = kn + (size_t)(k0 + (KB) * KTILE) * DD;              \
        const u16* vsrc_ = vT + (size_t)(k0 + (KB) * KTILE);                   \
        _Pragma("unroll")                                                      \
        for (int i_ = 0; i_ < 4; i_++) {                                       \
            int idx_ = (w * 4 + i_) * 64 + lane;                               \
            int kr_ = idx_ >> 3, kc_ = idx_ & 7;                               \
            GLOAD16(ksrc_ + (size_t)kr_ * DD + ((kc_ ^ (kr_ & 7)) * 8),        \
                    &sm.t[B].ks[(w * 4 + i_) * 512]);                          \
            int vr_ = idx_ >> 4, vc_ = idx_ & 15;                              \
            GLOAD16(vsrc_ + (size_t)vr_ * NK + ((vc_ ^ (vr_ & 7)) * 8),        \
                    &sm.t[B].vs[(w * 4 + i_) * 512]);                          \
        }                                                                      \
    } while (0)

    // stage Q once (swizzled, reg path)
    {
        int row = t >> 3, c = t & 7;
        *reinterpret_cast<uint4*>(&qs[row * 64 + ((c ^ (row & 7)) * 8)]) =
            *reinterpret_cast<const uint4*>(&qn[(size_t)(qb + row) * DD + c * 8]);
    }

    float rs_sum = 0.f;
    f32x16 pv0, pv1;
    #pragma unroll
    for (int i = 0; i < 16; i++) { pv0[i] = 0.f; pv1[i] = 0.f; }

    STAGE_KV(0, 0);
    __syncthreads();           // tile 0 + qs ready (compiler drains vmcnt/lgkm)

    int cur = 0;
    for (int kb = 0; kb < NT; kb++) {
        if (kb + 1 < NT) STAGE_KV(cur ^ 1, kb + 1);   // loads fly under compute

        const u16* ks_ = sm.t[cur].ks;
        const u16* vs_ = sm.t[cur].vs;

        // --- swapped QK^T: D[k][q], lane holds q=l31, k in regs ---
        f32x16 acc;
        #pragma unroll
        for (int i = 0; i < 16; i++) acc[i] = 0.f;
        #pragma unroll
        for (int s = 0; s < 4; s++) {
            int ca = 2 * s + half;
            int kr = kw + l31;
            bf16x8 af = *reinterpret_cast<const bf16x8*>(&ks_[kr * 64 + ((ca ^ (kr & 7)) * 8)]);
            bf16x8 bf = *reinterpret_cast<const bf16x8*>(&qs[l31 * 64 + ((ca ^ (l31 & 7)) * 8)]);
            acc = __builtin_amdgcn_mfma_f32_32x32x16_bf16(af, bf, acc, 0, 0, 0);
        }
        // exp + rowsum (k is reg axis: rs per q accumulates lane-locally)
        float e[16];
        #pragma unroll
        for (int r = 0; r < 16; r++) {
            e[r] = __expf(acc[r] * hc);
            rs_sum += e[r];
        }
        // --- build PV A-fragments in-register: cvt_pk + permlane32_swap ---
        bf16x8 pa[2];
        #pragma unroll
        for (int s = 0; s < 2; s++) {
            u32 x0 = cvtpk(e[8 * s + 0], e[8 * s + 1]);
            u32 y0 = cvtpk(e[8 * s + 4], e[8 * s + 5]);
            auto r0 = __builtin_amdgcn_permlane32_swap(x0, y0, false, false);
            u32 x1 = cvtpk(e[8 * s + 2], e[8 * s + 3]);
            u32 y1 = cvtpk(e[8 * s + 6], e[8 * s + 7]);
            auto r1 = __builtin_amdgcn_permlane32_swap(x1, y1, false, false);
            union { u32 u[4]; bf16x8 v; } f;
            f.u[0] = r0[0]; f.u[1] = r1[0]; f.u[2] = r0[1]; f.u[3] = r1[1];
            pa[s] = f.v;
        }
        // --- PV: D[q][d], this wave's own 32-k chunk only ---
        #pragma unroll
        for (int s = 0; s < 2; s++) {
            int cv = (kw >> 3) + 2 * s + half;
            int vr0 = l31, vr1 = 32 + l31;
            bf16x8 b0 = *reinterpret_cast<const bf16x8*>(&vs_[vr0 * 128 + ((cv ^ (vr0 & 7)) * 8)]);
            bf16x8 b1 = *reinterpret_cast<const bf16x8*>(&vs_[vr1 * 128 + ((cv ^ (vr1 & 7)) * 8)]);
            pv0 = __builtin_amdgcn_mfma_f32_32x32x16_bf16(pa[s], b0, pv0, 0, 0, 0);
            pv1 = __builtin_amdgcn_mfma_f32_32x32x16_bf16(pa[s], b1, pv1, 0, 0, 0);
        }

        __syncthreads();   // drains this iter's stage; closes reads of cur
        cur ^= 1;
    }

    // ---- epilogue: partial rowsum ----
    rs_sum += __shfl_xor(rs_sum, 32, 64);
    if (lane < 32) rs_ws[w][lane] = rs_sum;
    __syncthreads();   // all tile reads done before aliasing sm.ep
    if (t < 32)
        prs[(size_t)sp * NQ + qb + t] =
            rs_ws[0][t] + rs_ws[1][t] + rs_ws[2][t] + rs_ws[3][t];

    // ---- partial PV reduce across 4 waves ----
    float* redA = sm.ep.redA;
    float* redB = sm.ep.redB;
    if (w == 0) {
        #pragma unroll
        for (int r = 0; r < 16; r++) {
            int qq = (r & 3) + 8 * (r >> 2) + 4 * half;
            redA[qq * 64 + l31] = pv0[r];
            redA[qq * 64 + 32 + l31] = pv1[r];
        }
    } else if (w == 1) {
        #pragma unroll
        for (int r = 0; r < 16; r++) {
            int qq = (r & 3) + 8 * (r >> 2) + 4 * half;
            redB[qq * 64 + l31] = pv0[r];
            redB[qq * 64 + 32 + l31] = pv1[r];
        }
    }
    __syncthreads();
    if (w == 2) {
        #pragma unroll
        for (int r = 0; r < 16; r++) {
            int qq = (r & 3) + 8 * (r >> 2) + 4 * half;
            redA[qq * 64 + l31] += pv0[r];
            redA[qq * 64 + 32 + l31] += pv1[r];
        }
    } else if (w == 3) {
        #pragma unroll
        for (int r = 0; r < 16; r++) {
            int qq = (r & 3) + 8 * (r >> 2) + 4 * half;
            redB[qq * 64 + l31] += pv0[r];
            redB[qq * 64 + 32 + l31] += pv1[r];
        }
    }
    __syncthreads();
    float* dst = ppv + (size_t)sp * NQ * DD + (size_t)qb * DD;
    #pragma unroll
    for (int i = 0; i < 8; i++) {
        int idx = i * 256 + t;
        dst[idx] = redA[idx] + redB[idx];
    }
#undef STAGE_KV
}

// ---------------- Kernel 4: reduce split-K partials ----------------
__global__ void k_reduce(const float* __restrict__ prs, const float* __restrict__ ppv,
                         float* __restrict__ inv_rs, float* __restrict__ out_res) {
    int id = blockIdx.x * blockDim.x + threadIdx.x;   // 0 .. NQ*DD-1
    int n = id >> 6, d = id & 63;
    float s = prs[n] + prs[NQ + n] + prs[2 * NQ + n] + prs[3 * NQ + n];
    float inv = 1.0f / s;
    if (d == 0) inv_rs[n] = inv;
    const size_t st = (size_t)NQ * DD;
    float v = ppv[id] + ppv[st + id] + ppv[2 * st + id] + ppv[3 * st + id];
    out_res[id] = v * inv;
}

// ---------------- Kernel 5: recompute scores, write p_attn -------------------
// 64x64 tile per block; 4 waves = 4 quadrants of 32x32. Direct dword stores:
// each half-wave covers a contiguous 128B row segment (full 64B lines, no
// RMW) — drops the pl LDS transpose + barrier, 16 KB LDS total.
__global__ __launch_bounds__(256, 4) void
k_pwrite(const u16* __restrict__ qn, const u16* __restrict__ kn,
         const float* __restrict__ inv_rs, const int* __restrict__ hcp,
         float* __restrict__ out_p) {
    __shared__ __align__(16) u16 qs2[64 * 64];   // 8 KB
    __shared__ __align__(16) u16 ks2[64 * 64];   // 8 KB
    __shared__ float invl[64];

    const float hc = (float)hcp[0];
    const int bid = blockIdx.x;
    const int qb = (bid >> 7) * 64;
    const int kb = (bid & 127) * 64;
    const int t = threadIdx.x;
    const int w = t >> 6;
    const int lane = t & 63;
    const int l31 = lane & 31;
    const int half = lane >> 5;

    #pragma unroll
    for (int i = 0; i < 2; i++) {
        int idx16 = (w * 2 + i) * 64 + lane;
        int row = idx16 >> 3, c = idx16 & 7;
        GLOAD16(qn + (size_t)(qb + row) * DD + ((c ^ (row & 7)) * 8),
                &qs2[(w * 2 + i) * 512]);
        GLOAD16(kn + (size_t)(kb + row) * DD + ((c ^ (row & 7)) * 8),
                &ks2[(w * 2 + i) * 512]);
    }
    if (t < 64) invl[t] = inv_rs[qb + t];
    __syncthreads();

    const int wq = (w >> 1) * 32, wk = (w & 1) * 32;
    f32x16 acc;
    #pragma unroll
    for (int i = 0; i < 16; i++) acc[i] = 0.f;
    #pragma unroll
    for (int s = 0; s < 4; s++) {
        int ca = 2 * s + half;
        int qr = wq + l31, kr = wk + l31;
        bf16x8 a = *reinterpret_cast<const bf16x8*>(&qs2[qr * 64 + ((ca ^ (qr & 7)) * 8)]);
        bf16x8 b = *reinterpret_cast<const bf16x8*>(&ks2[kr * 64 + ((ca ^ (kr & 7)) * 8)]);
        acc = __builtin_amdgcn_mfma_f32_32x32x16_bf16(a, b, acc, 0, 0, 0);
    }
    #pragma unroll
    for (int r = 0; r < 16; r++) {
        int qq = wq + (r & 3) + 8 * (r >> 2) + 4 * half;
        out_p[(size_t)(qb + qq) * NK + kb + wk + l31] = __expf(acc[r] * hc) * invl[qq];
    }
}

extern "C" void kernel_launch(void* const* d_in, const int* in_sizes, int n_in,
                              void* d_out, int out_size, void* d_ws, size_t ws_size,
                              hipStream_t stream) {
    const float* q = (const float*)d_in[0];
    const float* k = (const float*)d_in[1];
    const float* v = (const float*)d_in[2];
    const int* hc = (const int*)d_in[3];

    float* out_res = (float*)d_out;
    float* out_p = out_res + (size_t)NQ * DD;

    char* wsb = (char*)d_ws;
    u16* qn = (u16*)wsb;
    u16* kn = qn + (size_t)NQ * DD;
    u16* vT = kn + (size_t)NK * DD;
    float* inv_rs = (float*)(vT + (size_t)NK * DD);

    const size_t base_need = 3 * (size_t)NQ * DD * 2 + (size_t)NQ * 4;
    const size_t extra_need = (size_t)KSPLIT * NQ * 4 + (size_t)KSPLIT * NQ * DD * 4;
    char* extra = (ws_size >= base_need + extra_need)
                      ? wsb + base_need
                      : (char*)out_p + ((size_t)NQ * NK * 4 - extra_need);
    float* prs = (float*)extra;                 // [KSPLIT][NQ]
    float* ppv = prs + (size_t)KSPLIT * NQ;     // [KSPLIT][NQ][DD]

    k_norm<<<1024, 256, 0, stream>>>(q, k, qn, kn);
    k_transv<<<NK / 64, 256, 0, stream>>>(v, vT);
    k_flash<<<(NQ / 32) * KSPLIT, 256, 0, stream>>>(qn, kn, vT, hc, prs, ppv);
    k_reduce<<<(NQ * DD) / 256, 256, 0, stream>>>(prs, ppv, inv_rs, out_res);
    k_pwrite<<<(NQ / 64) * (NK / 64), 256, 0, stream>>>(qn, kn, inv_rs, hc, out_p);
}